// Round 14
// baseline (142138.696 us; speedup 1.0000x reference)
//
#include <hip/hip_runtime.h>
#include <cstdint>
#include <cstddef>

#define NWG 32
#define NTHR 512
#define UPW 32  // hidden units per WG
#define TSTEPS 16384
#define HDIM 1024
#define EDIM 13
#define HLDIM 512

typedef unsigned long long ull;

// ---------------------------------------------------------------------------
// Init kernel: re-arm the tagged h-record ring and u-record every call (d_ws
// is poisoned once with 0xAA and never re-poisoned between graph replays; a
// finished replay also leaves end-state tags behind, so every tag word must
// be rewritten each launch).
// hrec[parity][i] = { low32: f32 h value, high32: u32 step tag }, 4 parities.
// ---------------------------------------------------------------------------
__global__ void k_init(const float* __restrict__ h0, ull* __restrict__ hrec,
                       ull* __restrict__ urec) {
  int i = threadIdx.x;
  hrec[i] = (ull)__float_as_uint(h0[i]);  // {h0, tag=0}
  hrec[HDIM + i] = 0ull;
  hrec[2 * HDIM + i] = 0ull;
  hrec[3 * HDIM + i] = 0ull;
  if (i < HLDIM) urec[i] = 0ull;
}

// ---------------------------------------------------------------------------
// Persistent LSTM kernel. R4/R13 protocol (best measured: 48.7 ms) with two
// bundled changes:
//  (1) 32 WGs x 512 thr (was 64): halves the rendezvous agent count ->
//      smaller max-of-N straggler tail + half the MALL probe contention.
//      Per-WG work doubles (32 units, 256 MACs/thread, W = 1 KB/thread
//      spill-streamed from scratch/L2 like R4 - rounds 3-13 proved VGPR
//      residency is unachievable and that spilled W streams fine).
//  (2) 4 threads/row + 4-way split accumulators: R4's single acc chain was
//      128 serial dependent FMAs (~0.2us); 4 chains of 64 cut the dep-stall
//      ~4x, and the row reduce shrinks to 2 shfl.
// Cross-WG sync unchanged (proven): self-validating {value, tag} 8-byte
// records in a 4-deep parity ring, relaxed agent-scope 64-bit atomics
// (single-copy, serviced at the device coherent point -> immune to
// non-coherent per-XCD L2s). One coherent round trip + one barrier per step.
// ---------------------------------------------------------------------------
__global__ __launch_bounds__(NTHR) void k_main(
    const float* __restrict__ x, const float* __restrict__ c0,
    const float* __restrict__ Wih, const float* __restrict__ Whh,
    const float* __restrict__ bih, const float* __restrict__ bhh,
    const float* __restrict__ W1, const float* __restrict__ b1,
    const float* __restrict__ W2, const float* __restrict__ b2,
    float* __restrict__ out, ull* hrec, ull* urec) {
  const int w = blockIdx.x;
  const int tid = threadIdx.x;
  const int sub4 = tid & 3;   // col-chunk index within row (4 x 256 cols)
  const int row = tid >> 2;   // local gate row 0..127
  const int wave = tid >> 6;  // 0..7
  const int lane = tid & 63;
  const int g = row & 3;      // 0=i 1=f 2=g 3=o
  const int lu = row >> 2;    // local unit 0..31 (= 4*wave + (lane>>4))
  const int grow = g * HDIM + w * UPW + lu;  // global gate row (gate-major)

  __shared__ float4 lds_h4[2][HDIM / 4];  // double-buffered by step parity
  __shared__ float lds_x[2][16];
  __shared__ float lds_wih[128][17];  // stride 17: conflict-free owner reads
  __shared__ float lds_bsum[128];
  __shared__ float lds_r0[8], lds_r1[8];
  float* lds_hf = (float*)lds_h4;  // [2][1024] flat

  // ---- load this thread's W_hh chunk (64 float4 = 256 cols), rotated so
  // the 4 distinct LDS b128 addresses per 16-lane group at compute time land
  // in 4 distinct bank quads (16-way same-address broadcast per address).
  float4 wreg[64];
  const float4* wrow = (const float4*)(Whh + (size_t)grow * HDIM) + sub4 * 64;
#pragma unroll
  for (int i = 0; i < 64; ++i) wreg[i] = wrow[(i + sub4) & 63];
  // Pin: asm claims to rewrite each value -> compiler spills to private
  // scratch (R4-proven: private reloads are hoistable above the poll/barrier
  // and pipeline during the sync wait) instead of rematerializing from
  // global inside the loop.
#pragma unroll
  for (int i = 0; i < 64; ++i)
    asm volatile("" : "+v"(wreg[i].x), "+v"(wreg[i].y), "+v"(wreg[i].z),
                     "+v"(wreg[i].w));

  if (tid < 128) {
    int g2 = tid & 3, lu2 = tid >> 2;
    int gr2 = g2 * HDIM + w * UPW + lu2;
#pragma unroll
    for (int e = 0; e < EDIM; ++e) lds_wih[tid][e] = Wih[gr2 * EDIM + e];
    lds_bsum[tid] = bih[gr2] + bhh[gr2];
  }
  // cell state: lanes 0,16,32,48 of wave v own units 4v+0..4v+3
  float cst = c0[w * UPW + 4 * wave + (lane >> 4)];
  __syncthreads();

  const float gsc = (g == 2) ? 2.f : 1.f;  // tanh via 2*sigmoid(2x)-1

  for (int t = 1; t <= TSTEPS; ++t) {
    const int lp = (t - 1) & 1;  // LDS parity (2-deep, barrier-separated)
    // ---- x_t prefetch: issue before the poll so its latency hides there
    float xv = 0.f;
    if (tid < EDIM) xv = x[(size_t)(t - 1) * EDIM + tid];

    // ---- poll this thread's two {h, tag} chunks of h_{t-1}; the poll load
    // IS the data load (one MALL round trip). 4-deep ring: overwrite of a
    // tag-t chunk (by tag t+4) needs three cross-WG dependence chains of
    // separation -> overwrite-before-read unreachable.
    const ull* src = hrec + (size_t)((t - 1) & 3) * HDIM;
    const unsigned want = (unsigned)(t - 1);
    ull v0 = __hip_atomic_load(&src[tid], __ATOMIC_RELAXED,
                               __HIP_MEMORY_SCOPE_AGENT);
    ull v1 = __hip_atomic_load(&src[tid + NTHR], __ATOMIC_RELAXED,
                               __HIP_MEMORY_SCOPE_AGENT);
    for (;;) {
      bool b0 = (unsigned)(v0 >> 32) == want;
      bool b1 = (unsigned)(v1 >> 32) == want;
      if (b0 && b1) break;
      if (!b0)
        v0 = __hip_atomic_load(&src[tid], __ATOMIC_RELAXED,
                               __HIP_MEMORY_SCOPE_AGENT);
      if (!b1)
        v1 = __hip_atomic_load(&src[tid + NTHR], __ATOMIC_RELAXED,
                               __HIP_MEMORY_SCOPE_AGENT);
    }
    lds_hf[lp * HDIM + tid] = __uint_as_float((unsigned)v0);
    lds_hf[lp * HDIM + tid + NTHR] = __uint_as_float((unsigned)v1);
    if (tid < EDIM) lds_x[lp][tid] = xv;
    __syncthreads();

    // ---- gate pre-activation: 256 MACs in 4 independent chains
    float a0 = 0.f, a1 = 0.f, a2 = 0.f, a3 = 0.f;
    if (sub4 == 0) {
      a0 = lds_bsum[row];
#pragma unroll
      for (int e = 0; e < EDIM; ++e) a0 += lds_wih[row][e] * lds_x[lp][e];
    }
#pragma unroll
    for (int i = 0; i < 64; ++i) {
      float4 hv = lds_h4[lp][sub4 * 64 + ((i + sub4) & 63)];
      float4 wv = wreg[i];
      float p = wv.x * hv.x + wv.y * hv.y + wv.z * hv.z + wv.w * hv.w;
      if ((i & 3) == 0) a0 += p;
      else if ((i & 3) == 1) a1 += p;
      else if ((i & 3) == 2) a2 += p;
      else a3 += p;
    }
    float acc = (a0 + a1) + (a2 + a3);
    acc += __shfl_xor(acc, 1);
    acc += __shfl_xor(acc, 2);

    // ---- activations computed in parallel on all lanes (one exp chain)
    float e = __expf(-gsc * acc);
    float y = 1.f / (1.f + e);
    float act = (g == 2) ? 2.f * y - 1.f : y;

    // gate acts of unit q live on lanes 16q + 4g (any of the 4 sub-lanes)
    int base = lane & 48;
    float ai = __shfl(act, base + 0);
    float af = __shfl(act, base + 4);
    float ag = __shfl(act, base + 8);
    float ao = __shfl(act, base + 12);
    if ((lane & 15) == 0) {
      cst = af * cst + ai * ag;
      float e2 = __expf(-2.f * cst);
      float hn = ao * (2.f / (1.f + e2) - 1.f);
      ull pk = ((ull)(unsigned)t << 32) | (ull)__float_as_uint(hn);
      __hip_atomic_store(&hrec[(size_t)(t & 3) * HDIM + w * UPW + 4 * wave +
                               (lane >> 4)],
                         pk, __ATOMIC_RELAXED, __HIP_MEMORY_SCOPE_AGENT);
    }
    // no end-of-step barrier: publish is self-validating; LDS buffer reuse is
    // two steps away and ordered by the intervening step's __syncthreads.
  }

  // ---- tail step 1: u = tanh(W1 @ h_T + b1), 16 rows per WG --------------
  {
    // h_T: tag TSTEPS lives in ring parity (TSTEPS & 3) == 0
    const unsigned want = (unsigned)TSTEPS;
    ull v0 = __hip_atomic_load(&hrec[tid], __ATOMIC_RELAXED,
                               __HIP_MEMORY_SCOPE_AGENT);
    ull v1 = __hip_atomic_load(&hrec[tid + NTHR], __ATOMIC_RELAXED,
                               __HIP_MEMORY_SCOPE_AGENT);
    for (;;) {
      bool b0 = (unsigned)(v0 >> 32) == want;
      bool b1 = (unsigned)(v1 >> 32) == want;
      if (b0 && b1) break;
      if (!b0)
        v0 = __hip_atomic_load(&hrec[tid], __ATOMIC_RELAXED,
                               __HIP_MEMORY_SCOPE_AGENT);
      if (!b1)
        v1 = __hip_atomic_load(&hrec[tid + NTHR], __ATOMIC_RELAXED,
                               __HIP_MEMORY_SCOPE_AGENT);
    }
    lds_hf[tid] = __uint_as_float((unsigned)v0);
    lds_hf[tid + NTHR] = __uint_as_float((unsigned)v1);
  }
  __syncthreads();
#pragma unroll
  for (int half = 0; half < 2; ++half) {
    int r1 = 16 * w + 8 * half + wave;  // 2 MLP rows per wave, 512 over 32 WG
    const float* w1p = W1 + (size_t)r1 * HDIM + lane * 16;
    float s0 = 0.f, s1 = 0.f;
#pragma unroll
    for (int i = 0; i < 16; i += 2) {
      s0 += w1p[i] * lds_hf[lane * 16 + i];
      s1 += w1p[i + 1] * lds_hf[lane * 16 + i + 1];
    }
    float acc1 = s0 + s1;
#pragma unroll
    for (int m = 1; m < 64; m <<= 1) acc1 += __shfl_xor(acc1, m);
    if (lane == 0) {
      float e2 = __expf(-2.f * (acc1 + b1[r1]));
      float u = 2.f / (1.f + e2) - 1.f;
      ull pk = (1ull << 32) | (ull)__float_as_uint(u);
      __hip_atomic_store(&urec[r1], pk, __ATOMIC_RELAXED,
                         __HIP_MEMORY_SCOPE_AGENT);
    }
  }

  // ---- tail step 2: out = W2 @ u + b2, WG 0 only -------------------------
  if (w == 0) {
    ull uv = __hip_atomic_load(&urec[tid], __ATOMIC_RELAXED,
                               __HIP_MEMORY_SCOPE_AGENT);
    while ((unsigned)(uv >> 32) != 1u)
      uv = __hip_atomic_load(&urec[tid], __ATOMIC_RELAXED,
                             __HIP_MEMORY_SCOPE_AGENT);
    float u = __uint_as_float((unsigned)uv);
    float p0 = W2[tid] * u;
    float p1 = W2[HLDIM + tid] * u;
#pragma unroll
    for (int m = 1; m < 64; m <<= 1) {
      p0 += __shfl_xor(p0, m);
      p1 += __shfl_xor(p1, m);
    }
    if (lane == 0) {
      lds_r0[wave] = p0;
      lds_r1[wave] = p1;
    }
    __syncthreads();
    if (tid == 0) {
      float o0 = b2[0], o1 = b2[1];
#pragma unroll
      for (int k = 0; k < 8; ++k) {
        o0 += lds_r0[k];
        o1 += lds_r1[k];
      }
      out[0] = o0;
      out[1] = o1;
    }
  }
}

extern "C" void kernel_launch(void* const* d_in, const int* in_sizes, int n_in,
                              void* d_out, int out_size, void* d_ws,
                              size_t ws_size, hipStream_t stream) {
  const float* x = (const float*)d_in[0];
  const float* h0 = (const float*)d_in[1];
  const float* c0 = (const float*)d_in[2];
  const float* Wih = (const float*)d_in[3];
  const float* Whh = (const float*)d_in[4];
  const float* bih = (const float*)d_in[5];
  const float* bhh = (const float*)d_in[6];
  const float* W1 = (const float*)d_in[7];
  const float* b1 = (const float*)d_in[8];
  const float* W2 = (const float*)d_in[9];
  const float* b2 = (const float*)d_in[10];
  float* out = (float*)d_out;

  ull* hrec = (ull*)d_ws;                                    // 4*1024*8 = 32 KB
  ull* urec = (ull*)((char*)d_ws + 4 * HDIM * sizeof(ull));  // 4 KB

  k_init<<<1, 1024, 0, stream>>>(h0, hrec, urec);
  k_main<<<NWG, NTHR, 0, stream>>>(x, c0, Wih, Whh, bih, bhh, W1, b1, W2, b2,
                                   out, hrec, urec);
}

// Round 15
// 73575.525 us; speedup vs baseline: 1.9319x; 1.9319x over previous
//
#include <hip/hip_runtime.h>
#include <cstdint>
#include <cstddef>

#define NWG 128
#define NTHR 512
#define UPW 8  // hidden units per WG
#define TSTEPS 16384
#define HDIM 1024
#define EDIM 13
#define HLDIM 512

typedef unsigned long long ull;

// ---------------------------------------------------------------------------
// Init kernel: re-arm the tagged h-record ring and u-record every call (d_ws
// is poisoned once with 0xAA and never re-poisoned between graph replays; a
// finished replay also leaves end-state tags behind, so every tag word must
// be rewritten each launch).
// hrec[parity][i] = { low32: f32 h value, high32: u32 step tag }, 4 parities.
// ---------------------------------------------------------------------------
__global__ void k_init(const float* __restrict__ h0, ull* __restrict__ hrec,
                       ull* __restrict__ urec) {
  int i = threadIdx.x;
  hrec[i] = (ull)__float_as_uint(h0[i]);  // {h0, tag=0}
  hrec[HDIM + i] = 0ull;
  hrec[2 * HDIM + i] = 0ull;
  hrec[3 * HDIM + i] = 0ull;
  if (i < HLDIM) urec[i] = 0ull;
}

// ---------------------------------------------------------------------------
// Persistent LSTM kernel. The R14 lesson, quantified: per-step wall =
// W-bytes-streamed-per-WG / per-CU L2 BW (~135 GB/s). R13: 256 KB -> 1.9us
// (+sync ~1.2 = 3.0 measured). R14: 512 KB over half the CUs -> 8.7us.
// Fix: SHRINK the per-thread W chunk until it FITS the granted VGPR budget.
// 128 WGs x 512 thr, 8 units/WG -> 64 W floats/thread = 16 float4s = 64
// VGPRs. R14 proved the allocator grants 128 VGPRs to 512-thread WGs under
// pressure; 64 W + ~35 working fits -> no spill, no W-stream at all. (R5's
// 16-float4 attempt failed only because 1024-thread WGs got a 60-VGPR
// budget.) Remaining per-step cost = pure sync chain.
// Wave v owns unit 8w+v: rows 4v+g live in the wave's four 16-lane groups;
// 16 threads/row x 64 cols; in-wave xor-reduce (1,2,4,8); lane 0 integrates
// c and publishes. 8 publishes/WG.
// Cross-WG sync unchanged (proven): self-validating {value, tag} 8-byte
// records in a 4-deep parity ring, relaxed agent-scope 64-bit atomics
// (single-copy, serviced at the device coherent point -> immune to
// non-coherent per-XCD L2s). One coherent round trip + one barrier per step.
// ---------------------------------------------------------------------------
__global__ __launch_bounds__(NTHR) void k_main(
    const float* __restrict__ x, const float* __restrict__ c0,
    const float* __restrict__ Wih, const float* __restrict__ Whh,
    const float* __restrict__ bih, const float* __restrict__ bhh,
    const float* __restrict__ W1, const float* __restrict__ b1,
    const float* __restrict__ W2, const float* __restrict__ b2,
    float* __restrict__ out, ull* hrec, ull* urec) {
  const int w = blockIdx.x;
  const int tid = threadIdx.x;
  const int wave = tid >> 6;        // 0..7 == local unit
  const int lane = tid & 63;
  const int g = (tid >> 4) & 3;     // gate row within the unit
  const int sub = tid & 15;         // 16 threads/row, 64 cols each
  const int row = wave * 4 + g;     // local gate row 0..31
  const int grow = g * HDIM + w * UPW + wave;  // global gate row

  __shared__ float4 lds_h4[2][HDIM / 4];  // double-buffered by step parity
  __shared__ float lds_x[2][16];
  __shared__ float lds_wih[32][17];  // stride 17: conflict-free owner reads
  __shared__ float lds_bsum[32];
  __shared__ float lds_r0[8], lds_r1[8];
  float* lds_hf = (float*)lds_h4;  // [2][1024] flat

  // ---- load this thread's W_hh chunk (16 float4 = 64 cols), rotated so the
  // 16 distinct b128 addresses per 16-lane group spread across banks (2-way
  // aliasing over 32 banks = free), same-address broadcast across the wave's
  // 4 groups.
  float4 wreg[16];
  const float4* wrow = (const float4*)(Whh + (size_t)grow * HDIM);
#pragma unroll
  for (int i = 0; i < 16; ++i) wreg[i] = wrow[sub * 16 + ((i + sub) & 15)];
  // Pin in VGPRs: 64 regs of W + ~35 working fits the 128-VGPR grant ->
  // true residency (no scratch, no rematerialization).
#pragma unroll
  for (int i = 0; i < 16; ++i)
    asm volatile("" : "+v"(wreg[i].x), "+v"(wreg[i].y), "+v"(wreg[i].z),
                     "+v"(wreg[i].w));

  if (tid < 32) {
    int lu2 = tid >> 2, g2 = tid & 3;
    int gr2 = g2 * HDIM + w * UPW + lu2;
#pragma unroll
    for (int e = 0; e < EDIM; ++e) lds_wih[lu2 * 4 + g2][e] = Wih[gr2 * EDIM + e];
    lds_bsum[lu2 * 4 + g2] = bih[gr2] + bhh[gr2];
  }
  // cell state: lane 0 of wave v owns unit 8w+v
  float cst = c0[w * UPW + wave];
  __syncthreads();

  const float gsc = (g == 2) ? 2.f : 1.f;  // tanh via 2*sigmoid(2x)-1

  for (int t = 1; t <= TSTEPS; ++t) {
    const int lp = (t - 1) & 1;  // LDS parity (2-deep, barrier-separated)
    // ---- x_t prefetch: issue before the poll so its latency hides there
    float xv = 0.f;
    if (tid < EDIM) xv = x[(size_t)(t - 1) * EDIM + tid];

    // ---- poll this thread's two {h, tag} chunks of h_{t-1}; the poll load
    // IS the data load (one MALL round trip). 4-deep ring: overwrite of a
    // tag-t chunk (by tag t+4) needs three cross-WG dependence chains of
    // separation -> overwrite-before-read unreachable.
    const ull* src = hrec + (size_t)((t - 1) & 3) * HDIM;
    const unsigned want = (unsigned)(t - 1);
    ull v0 = __hip_atomic_load(&src[tid], __ATOMIC_RELAXED,
                               __HIP_MEMORY_SCOPE_AGENT);
    ull v1 = __hip_atomic_load(&src[tid + NTHR], __ATOMIC_RELAXED,
                               __HIP_MEMORY_SCOPE_AGENT);
    for (;;) {
      bool b0 = (unsigned)(v0 >> 32) == want;
      bool b1 = (unsigned)(v1 >> 32) == want;
      if (b0 && b1) break;
      if (!b0)
        v0 = __hip_atomic_load(&src[tid], __ATOMIC_RELAXED,
                               __HIP_MEMORY_SCOPE_AGENT);
      if (!b1)
        v1 = __hip_atomic_load(&src[tid + NTHR], __ATOMIC_RELAXED,
                               __HIP_MEMORY_SCOPE_AGENT);
    }
    lds_hf[lp * HDIM + tid] = __uint_as_float((unsigned)v0);
    lds_hf[lp * HDIM + tid + NTHR] = __uint_as_float((unsigned)v1);
    if (tid < EDIM) lds_x[lp][tid] = xv;
    __syncthreads();

    // ---- gate pre-activation: 64 MACs in 4 independent chains
    float a0 = 0.f, a1 = 0.f, a2 = 0.f, a3 = 0.f;
    if (sub == 0) {
      a0 = lds_bsum[row];
#pragma unroll
      for (int e = 0; e < EDIM; ++e) a0 += lds_wih[row][e] * lds_x[lp][e];
    }
#pragma unroll
    for (int i = 0; i < 16; ++i) {
      float4 hv = lds_h4[lp][sub * 16 + ((i + sub) & 15)];
      float4 wv = wreg[i];
      float p = wv.x * hv.x + wv.y * hv.y + wv.z * hv.z + wv.w * hv.w;
      if ((i & 3) == 0) a0 += p;
      else if ((i & 3) == 1) a1 += p;
      else if ((i & 3) == 2) a2 += p;
      else a3 += p;
    }
    float acc = (a0 + a1) + (a2 + a3);
    acc += __shfl_xor(acc, 1);
    acc += __shfl_xor(acc, 2);
    acc += __shfl_xor(acc, 4);
    acc += __shfl_xor(acc, 8);

    // ---- activations: each 16-lane group holds its gate sum (one exp each)
    float e = __expf(-gsc * acc);
    float y = 1.f / (1.f + e);
    float act = (g == 2) ? 2.f * y - 1.f : y;

    // gates of this wave's unit live at lanes 0,16,32,48
    float ai = __shfl(act, 0);
    float af = __shfl(act, 16);
    float ag = __shfl(act, 32);
    float ao = __shfl(act, 48);
    if (lane == 0) {
      cst = af * cst + ai * ag;
      float e2 = __expf(-2.f * cst);
      float hn = ao * (2.f / (1.f + e2) - 1.f);
      ull pk = ((ull)(unsigned)t << 32) | (ull)__float_as_uint(hn);
      __hip_atomic_store(&hrec[(size_t)(t & 3) * HDIM + w * UPW + wave], pk,
                         __ATOMIC_RELAXED, __HIP_MEMORY_SCOPE_AGENT);
    }
    // no end-of-step barrier: publish is self-validating; LDS buffer reuse is
    // two steps away and ordered by the intervening step's __syncthreads.
  }

  // ---- tail step 1: u = tanh(W1 @ h_T + b1), 4 rows per WG ---------------
  {
    // h_T: tag TSTEPS lives in ring parity (TSTEPS & 3) == 0
    const unsigned want = (unsigned)TSTEPS;
    ull v0 = __hip_atomic_load(&hrec[tid], __ATOMIC_RELAXED,
                               __HIP_MEMORY_SCOPE_AGENT);
    ull v1 = __hip_atomic_load(&hrec[tid + NTHR], __ATOMIC_RELAXED,
                               __HIP_MEMORY_SCOPE_AGENT);
    for (;;) {
      bool b0 = (unsigned)(v0 >> 32) == want;
      bool b1 = (unsigned)(v1 >> 32) == want;
      if (b0 && b1) break;
      if (!b0)
        v0 = __hip_atomic_load(&hrec[tid], __ATOMIC_RELAXED,
                               __HIP_MEMORY_SCOPE_AGENT);
      if (!b1)
        v1 = __hip_atomic_load(&hrec[tid + NTHR], __ATOMIC_RELAXED,
                               __HIP_MEMORY_SCOPE_AGENT);
    }
    lds_hf[tid] = __uint_as_float((unsigned)v0);
    lds_hf[tid + NTHR] = __uint_as_float((unsigned)v1);
  }
  __syncthreads();
  if (wave < 4) {
    int r1 = 4 * w + wave;  // one MLP row per wave, 512 rows over 128 WGs
    const float* w1p = W1 + (size_t)r1 * HDIM + lane * 16;
    float s0 = 0.f, s1 = 0.f;
#pragma unroll
    for (int i = 0; i < 16; i += 2) {
      s0 += w1p[i] * lds_hf[lane * 16 + i];
      s1 += w1p[i + 1] * lds_hf[lane * 16 + i + 1];
    }
    float acc1 = s0 + s1;
#pragma unroll
    for (int m = 1; m < 64; m <<= 1) acc1 += __shfl_xor(acc1, m);
    if (lane == 0) {
      float e2 = __expf(-2.f * (acc1 + b1[r1]));
      float u = 2.f / (1.f + e2) - 1.f;
      ull pk = (1ull << 32) | (ull)__float_as_uint(u);
      __hip_atomic_store(&urec[r1], pk, __ATOMIC_RELAXED,
                         __HIP_MEMORY_SCOPE_AGENT);
    }
  }

  // ---- tail step 2: out = W2 @ u + b2, WG 0 only -------------------------
  if (w == 0) {
    ull uv = __hip_atomic_load(&urec[tid], __ATOMIC_RELAXED,
                               __HIP_MEMORY_SCOPE_AGENT);
    while ((unsigned)(uv >> 32) != 1u)
      uv = __hip_atomic_load(&urec[tid], __ATOMIC_RELAXED,
                             __HIP_MEMORY_SCOPE_AGENT);
    float u = __uint_as_float((unsigned)uv);
    float p0 = W2[tid] * u;
    float p1 = W2[HLDIM + tid] * u;
#pragma unroll
    for (int m = 1; m < 64; m <<= 1) {
      p0 += __shfl_xor(p0, m);
      p1 += __shfl_xor(p1, m);
    }
    if (lane == 0) {
      lds_r0[wave] = p0;
      lds_r1[wave] = p1;
    }
    __syncthreads();
    if (tid == 0) {
      float o0 = b2[0], o1 = b2[1];
#pragma unroll
      for (int k = 0; k < 8; ++k) {
        o0 += lds_r0[k];
        o1 += lds_r1[k];
      }
      out[0] = o0;
      out[1] = o1;
    }
  }
}

extern "C" void kernel_launch(void* const* d_in, const int* in_sizes, int n_in,
                              void* d_out, int out_size, void* d_ws,
                              size_t ws_size, hipStream_t stream) {
  const float* x = (const float*)d_in[0];
  const float* h0 = (const float*)d_in[1];
  const float* c0 = (const float*)d_in[2];
  const float* Wih = (const float*)d_in[3];
  const float* Whh = (const float*)d_in[4];
  const float* bih = (const float*)d_in[5];
  const float* bhh = (const float*)d_in[6];
  const float* W1 = (const float*)d_in[7];
  const float* b1 = (const float*)d_in[8];
  const float* W2 = (const float*)d_in[9];
  const float* b2 = (const float*)d_in[10];
  float* out = (float*)d_out;

  ull* hrec = (ull*)d_ws;                                    // 4*1024*8 = 32 KB
  ull* urec = (ull*)((char*)d_ws + 4 * HDIM * sizeof(ull));  // 4 KB

  k_init<<<1, 1024, 0, stream>>>(h0, hrec, urec);
  k_main<<<NWG, NTHR, 0, stream>>>(x, c0, Wih, Whh, bih, bhh, W1, b1, W2, b2,
                                   out, hrec, urec);
}